// Round 2
// baseline (12125.706 us; speedup 1.0000x reference)
//
#include <hip/hip_runtime.h>
#include <hip/hip_fp16.h>

// AffineCouplingBlock on MI355X — Round 1 (resubmit: round-1 bench was a GPU
// acquisition timeout, no signal). Exact f32 VALU baseline / correctness anchor.
// B=64, T=4096, C=64, H=W=64, COND=16, IN=81, HID=128.
// d_in: 0=x[64,4096,2] 1=w[64,64,64,64] 2=cond[64,16] 3=W0[4,128,81] 4=b0[4,128]
//       5=W1[4,3,128,128] 6=b1[4,3,128] 7=W2[4,1,128] 8=b2[4,1]   (all f32)
// d_out: z[64,4096,2] (524288 floats) then log_det[64].

#define NPTS (64 * 4096)
#define ZSIZE (NPTS * 2)

// ---------------------------------------------------------------------------
// Prep: transpose weights into ws (Wt[k][o] layout so the MLP inner loop reads
// 16 consecutive wave-uniform floats per k -> s_load_dwordx4 batches), and zero
// the log_det accumulator region of d_out.
// ---------------------------------------------------------------------------
__global__ void prep_kernel(const float* __restrict__ W0, const float* __restrict__ W1,
                            float* __restrict__ Wt0, float* __restrict__ Wt1,
                            float* __restrict__ out_ld) {
    const int tid0 = blockIdx.x * blockDim.x + threadIdx.x;
    const int stride = gridDim.x * blockDim.x;
    if (tid0 < 64) out_ld[tid0] = 0.f;
    // Wt0[i][k][o] <- W0[i][o][k]   (4 x 81 x 128)
    for (int idx = tid0; idx < 4 * 81 * 128; idx += stride) {
        const int o = idx & 127;
        const int rest = idx >> 7;
        const int k = rest % 81;
        const int i = rest / 81;
        Wt0[idx] = W0[(i * 128 + o) * 81 + k];
    }
    // Wt1[m][k][o] <- W1[m][o][k]   (12 x 128 x 128), m = i*3+j
    for (int idx = tid0; idx < 12 * 128 * 128; idx += stride) {
        const int o = idx & 127;
        const int k = (idx >> 7) & 127;
        const int m = idx >> 14;
        Wt1[idx] = W1[(m * 128 + o) * 128 + k];
    }
}

// ---------------------------------------------------------------------------
// Fused stage kernel: grid-sample + both MLP chains (s and t) + z update +
// log_det partial sum.  STAGE=0: z_a' = z_a*exp(s)+t (coords from x).
// STAGE=1: z_b' = z_b*exp(s)+t (coords from [z_a', z_b]).
// One thread per point; h kept in LDS columns (lane-private -> conflict-free,
// no __syncthreads needed anywhere). Weights are wave-uniform -> scalar loads.
// Known structural limit: 64KiB LDS/block @ 1 wave/block -> 2 waves/CU (2 of 4
// SIMDs idle). Accepted for the correctness anchor; MFMA rewrite comes next.
// ---------------------------------------------------------------------------
template <int STAGE>
__global__ __launch_bounds__(64) void stage_kernel(
    const float* __restrict__ x, const float* __restrict__ w,
    const float* __restrict__ cond,
    const float* __restrict__ Wt0, const float* __restrict__ b0,
    const float* __restrict__ Wt1, const float* __restrict__ b1,
    const float* __restrict__ W2, const float* __restrict__ b2,
    float* __restrict__ out) {
    __shared__ float hb[2][128][64];  // 64 KiB, double-buffered activations

    const int tid = threadIdx.x;
    const int p = blockIdx.x * 64 + tid;
    const int b = p >> 12;  // T = 4096 points per batch, uniform per block

    const float xa = x[2 * p];
    const float xb = x[2 * p + 1];

    float cz0, cz1, c0, zmod;
    if (STAGE == 0) {
        cz0 = xa; cz1 = xb; c0 = xb; zmod = xa;
    } else {
        cz0 = out[2 * p];  // z_a' written by stage A
        cz1 = xb; c0 = cz0; zmod = xb;
    }

    // ---- bilinear grid sample, align_corners=True, zeros padding ----
    const float gx = cz0 * 2.f - 1.f, gy = cz1 * 2.f - 1.f;
    const float ix = (gx + 1.f) * 0.5f * 63.f;
    const float iy = (gy + 1.f) * 0.5f * 63.f;
    const float ix0 = floorf(ix), iy0 = floorf(iy);
    const float ix1 = ix0 + 1.f, iy1 = iy0 + 1.f;
    const float wx1 = ix - ix0, wx0 = 1.f - wx1;
    const float wy1 = iy - iy0, wy0 = 1.f - wy1;
    const bool vx0 = (ix0 >= 0.f) && (ix0 <= 63.f);
    const bool vx1 = (ix1 >= 0.f) && (ix1 <= 63.f);
    const bool vy0 = (iy0 >= 0.f) && (iy0 <= 63.f);
    const bool vy1 = (iy1 >= 0.f) && (iy1 <= 63.f);
    const float f00 = (vy0 && vx0) ? wy0 * wx0 : 0.f;
    const float f01 = (vy0 && vx1) ? wy0 * wx1 : 0.f;
    const float f10 = (vy1 && vx0) ? wy1 * wx0 : 0.f;
    const float f11 = (vy1 && vx1) ? wy1 * wx1 : 0.f;
    const int xi0 = (int)fminf(fmaxf(ix0, 0.f), 63.f);
    const int xi1 = (int)fminf(fmaxf(ix1, 0.f), 63.f);
    const int yi0 = (int)fminf(fmaxf(iy0, 0.f), 63.f);
    const int yi1 = (int)fminf(fmaxf(iy1, 0.f), 63.f);

    const float* wb = w + ((size_t)b << 18);  // b * 64*64*64
    const int o00 = yi0 * 64 + xi0, o01 = yi0 * 64 + xi1;
    const int o10 = yi1 * 64 + xi0, o11 = yi1 * 64 + xi1;

    float lf[64];
#pragma unroll
    for (int c = 0; c < 64; ++c) {
        const float* wc = wb + (c << 12);
        lf[c] = f00 * wc[o00] + f01 * wc[o01] + f10 * wc[o10] + f11 * wc[o11];
    }

    // cond is block-uniform -> lives in SGPRs
    float cnd[16];
#pragma unroll
    for (int j = 0; j < 16; ++j) cnd[j] = cond[b * 16 + j];

    float results[2];
    for (int chain = 0; chain < 2; ++chain) {
        const int idx = STAGE * 2 + chain;
        int src = chain;  // chain0 starts in buf0, chain1 in buf1 (no aliasing)
        // write comb = [z_keep, lf(64), cond(16)] into hb[src]
        hb[src][0][tid] = c0;
#pragma unroll
        for (int c = 0; c < 64; ++c) hb[src][1 + c][tid] = lf[c];
#pragma unroll
        for (int j = 0; j < 16; ++j) hb[src][65 + j][tid] = cnd[j];

        for (int l = 0; l < 4; ++l) {
            const float* Wl = (l == 0) ? (Wt0 + idx * 81 * 128)
                                       : (Wt1 + (idx * 3 + (l - 1)) * 128 * 128);
            const float* bl = (l == 0) ? (b0 + idx * 128) : (b1 + (idx * 3 + (l - 1)) * 128);
            const int K = (l == 0) ? 81 : 128;
            const int dst = 1 - src;
            for (int ot = 0; ot < 8; ++ot) {
                float acc[16];
#pragma unroll
                for (int o = 0; o < 16; ++o) acc[o] = bl[ot * 16 + o];
                const float* Wp = Wl + ot * 16;
#pragma unroll 4
                for (int k = 0; k < K; ++k) {
                    const float hk = hb[src][k][tid];
                    const float* wr = Wp + (k << 7);
#pragma unroll
                    for (int o = 0; o < 16; ++o) acc[o] = fmaf(hk, wr[o], acc[o]);
                }
#pragma unroll
                for (int o = 0; o < 16; ++o) {
                    const float v = acc[o];
                    // silu(v) = v * sigmoid(v)
                    const float sv = v * __builtin_amdgcn_rcpf(1.f + __expf(-v));
                    hb[dst][ot * 16 + o][tid] = sv;
                }
            }
            src = dst;
        }
        // output layer: dot(h, W2[idx]) + b2[idx]
        const float* w2 = W2 + (idx << 7);
        float y = b2[idx];
#pragma unroll 4
        for (int k = 0; k < 128; ++k) y = fmaf(hb[src][k][tid], w2[k], y);
        results[chain] = y;
    }

    const float s = 1.5f * tanhf(results[0]);
    const float zn = zmod * expf(s) + results[1];
    out[2 * p + STAGE] = zn;

    // log_det partial: wave-reduce s, one atomic per wave
    float v = s;
#pragma unroll
    for (int off = 32; off > 0; off >>= 1) v += __shfl_down(v, off);
    if (tid == 0) atomicAdd(out + ZSIZE + b, v);
}

// ---------------------------------------------------------------------------
extern "C" void kernel_launch(void* const* d_in, const int* in_sizes, int n_in,
                              void* d_out, int out_size, void* d_ws, size_t ws_size,
                              hipStream_t stream) {
    const float* x = (const float*)d_in[0];
    const float* w = (const float*)d_in[1];
    const float* cond = (const float*)d_in[2];
    const float* W0 = (const float*)d_in[3];
    const float* b0 = (const float*)d_in[4];
    const float* W1 = (const float*)d_in[5];
    const float* b1 = (const float*)d_in[6];
    const float* W2 = (const float*)d_in[7];
    const float* b2 = (const float*)d_in[8];
    float* out = (float*)d_out;

    float* Wt0 = (float*)d_ws;            // 4*81*128 floats
    float* Wt1 = Wt0 + 4 * 81 * 128;      // 12*128*128 floats (total ws ~0.95 MB)

    prep_kernel<<<512, 256, 0, stream>>>(W0, W1, Wt0, Wt1, out + ZSIZE);
    stage_kernel<0><<<NPTS / 64, 64, 0, stream>>>(x, w, cond, Wt0, b0, Wt1, b1, W2, b2, out);
    stage_kernel<1><<<NPTS / 64, 64, 0, stream>>>(x, w, cond, Wt0, b0, Wt1, b1, W2, b2, out);
}

// Round 3
// 581.716 us; speedup vs baseline: 20.8447x; 20.8447x over previous
//
#include <hip/hip_runtime.h>
#include <hip/hip_fp16.h>

// AffineCouplingBlock MI355X — Round 3: fp16 MFMA (split hi/lo weights), wave-
// private 32-point pipeline, no mid-kernel __syncthreads, XCD-swizzled grid.
// B=64,T=4096,C=64,H=W=64,COND=16,IN=81(->96 pad),HID=128.
// comb col layout (K-permuted in prep): [lf 0..63][cond 64..79][z 80][0 81..95]

#define NPTS (64 * 4096)
#define ZSIZE (NPTS * 2)

typedef _Float16 f16x8 __attribute__((ext_vector_type(8)));
typedef float f32x4 __attribute__((ext_vector_type(4)));

// intra-wave LDS RAW fence (rule #18: lgkmcnt + sched_barrier)
#define LDS_FENCE()                                        \
    do {                                                   \
        asm volatile("s_waitcnt lgkmcnt(0)" ::: "memory"); \
        __builtin_amdgcn_sched_barrier(0);                 \
    } while (0)

// ws layout (halfs): W0f [4][3][8][{hi,lo}x512] | W1f [12][4][8][1024] | W2h [4][128]
#define W0F_HALFS (4 * 3 * 8 * 1024)   // 98304
#define W1F_HALFS (12 * 4 * 8 * 1024)  // 393216

// ---------------------------------------------------------------------------
// Prep: fragmentize weights into per-lane-coalesced fp16 hi/lo chunks.
// Fragment slot (lane=16g+c, j) holds B[k=kt*32+8g+j][n=n0*16+c] = W[n][k'].
// A-frags use the same slot->k map, so any HW k-order bijection cancels.
// ---------------------------------------------------------------------------
__global__ void prep_kernel(const float* __restrict__ W0, const float* __restrict__ W1,
                            const float* __restrict__ W2, _Float16* __restrict__ W0f,
                            _Float16* __restrict__ W1f, _Float16* __restrict__ W2h,
                            float* __restrict__ out_ld) {
    const int t0 = blockIdx.x * blockDim.x + threadIdx.x;
    const int stride = gridDim.x * blockDim.x;
    if (t0 < 64) out_ld[t0] = 0.f;
    // W0: [4][128][81] -> padded K=96 with col permutation (new k: 0..79 <- old k+1, 80 <- old 0)
    for (int t = t0; t < 4 * 3 * 8 * 64 * 8; t += stride) {
        int j = t & 7, r = t >> 3;
        int l = r & 63; r >>= 6;
        int n0 = r & 7; r >>= 3;
        int kt = r % 3, idx = r / 3;
        int k = kt * 32 + (l >> 4) * 8 + j;
        int n = n0 * 16 + (l & 15);
        float v = 0.f;
        if (k <= 80) {
            int ko = (k < 80) ? (k + 1) : 0;
            v = W0[(idx * 128 + n) * 81 + ko];
        }
        _Float16 hi = (_Float16)v;
        _Float16 lo = (_Float16)(v - (float)hi);
        int base = ((idx * 3 + kt) * 8 + n0) * 1024;
        W0f[base + l * 8 + j] = hi;
        W0f[base + 512 + l * 8 + j] = lo;
    }
    // W1: [12][128][128]
    for (int t = t0; t < 12 * 4 * 8 * 64 * 8; t += stride) {
        int j = t & 7, r = t >> 3;
        int l = r & 63; r >>= 6;
        int n0 = r & 7; r >>= 3;
        int kt = r & 3, m = r >> 2;
        int k = kt * 32 + (l >> 4) * 8 + j;
        int n = n0 * 16 + (l & 15);
        float v = W1[(m * 128 + n) * 128 + k];
        _Float16 hi = (_Float16)v;
        _Float16 lo = (_Float16)(v - (float)hi);
        int base = ((m * 4 + kt) * 8 + n0) * 1024;
        W1f[base + l * 8 + j] = hi;
        W1f[base + 512 + l * 8 + j] = lo;
    }
    for (int t = t0; t < 512; t += stride) W2h[t] = (_Float16)W2[t];
}

// ---------------------------------------------------------------------------
template <int STAGE>
__global__ __launch_bounds__(256) void stage_kernel(
    const float* __restrict__ x, const float* __restrict__ w, const float* __restrict__ cond,
    const _Float16* __restrict__ W0f, const float* __restrict__ b0,
    const _Float16* __restrict__ W1f, const float* __restrict__ b1,
    const _Float16* __restrict__ W2h, const float* __restrict__ b2,
    float* __restrict__ out) {
    // 4 waves x 32 rows x 136 halfs (136 pad: frag b128 reads ~canonical profile)
    __shared__ __align__(16) _Float16 hlds[4][32][136];
    __shared__ __align__(8) _Float16 w2l[4][128];

    const int tid = threadIdx.x;
    ((unsigned int*)w2l)[tid] = ((const unsigned int*)W2h)[tid];  // 512 halfs = 256 dwords
    __syncthreads();  // only block-wide barrier

    const int o = blockIdx.x;
    const int wg = (o & 7) * 256 + (o >> 3);  // XCD-bijective swizzle (2048 = 8*256)
    const int wv = tid >> 6, lane = tid & 63;
    const int pl = lane & 31;  // local point
    const int hh = lane >> 5;  // channel-half
    const int p = wg * 128 + wv * 32 + pl;
    const int b = p >> 12;

    const float xa = x[2 * p], xb = x[2 * p + 1];
    float cz0, cz1, c0z, zmod;
    if (STAGE == 0) {
        cz0 = xa; cz1 = xb; c0z = xb; zmod = xa;
    } else {
        cz0 = out[2 * p]; cz1 = xb; c0z = cz0; zmod = xb;
    }

    // ---- bilinear params (replicates reference FP order) ----
    const float gx = cz0 * 2.f - 1.f, gy = cz1 * 2.f - 1.f;
    const float ixf = (gx + 1.f) * 0.5f * 63.f;
    const float iyf = (gy + 1.f) * 0.5f * 63.f;
    const float ix0f = floorf(ixf), iy0f = floorf(iyf);
    const float ix1f = ix0f + 1.f, iy1f = iy0f + 1.f;
    const float wx1 = ixf - ix0f, wx0 = 1.f - wx1;
    const float wy1 = iyf - iy0f, wy0 = 1.f - wy1;
    const bool vx0 = (ix0f >= 0.f) && (ix0f <= 63.f);
    const bool vx1 = (ix1f >= 0.f) && (ix1f <= 63.f);
    const bool vy0 = (iy0f >= 0.f) && (iy0f <= 63.f);
    const bool vy1 = (iy1f >= 0.f) && (iy1f <= 63.f);
    const float f00 = (vy0 && vx0) ? wy0 * wx0 : 0.f;
    const float f01 = (vy0 && vx1) ? wy0 * wx1 : 0.f;
    const float f10 = (vy1 && vx0) ? wy1 * wx0 : 0.f;
    const float f11 = (vy1 && vx1) ? wy1 * wx1 : 0.f;
    const int xi0 = (int)fminf(fmaxf(ix0f, 0.f), 63.f);
    const int xi1 = (int)fminf(fmaxf(ix1f, 0.f), 63.f);
    const int yi0 = (int)fminf(fmaxf(iy0f, 0.f), 63.f);
    const int yi1 = (int)fminf(fmaxf(iy1f, 0.f), 63.f);
    const int o00 = yi0 * 64 + xi0, o01 = yi0 * 64 + xi1;
    const int o10 = yi1 * 64 + xi0, o11 = yi1 * 64 + xi1;

    // ---- gather: 32 channels per lane -> comb cols [hh*32 .. +31] ----
    const float* wb = w + ((size_t)b << 18) + ((size_t)(hh * 32) << 12);
#pragma unroll 4
    for (int jj = 0; jj < 16; ++jj) {
        const float* wcA = wb + ((2 * jj) << 12);
        const float* wcB = wcA + 4096;
        const float lfA = f00 * wcA[o00] + f01 * wcA[o01] + f10 * wcA[o10] + f11 * wcA[o11];
        const float lfB = f00 * wcB[o00] + f01 * wcB[o01] + f10 * wcB[o10] + f11 * wcB[o11];
        *(__half2*)&hlds[wv][pl][hh * 32 + 2 * jj] = __floats2half2_rn(lfA, lfB);
    }
    if (hh == 0) {  // cond 64..79, z 80, zeros 81..95
        const float* cb = cond + b * 16;
#pragma unroll
        for (int j2 = 0; j2 < 8; ++j2)
            *(__half2*)&hlds[wv][pl][64 + 2 * j2] = __floats2half2_rn(cb[2 * j2], cb[2 * j2 + 1]);
        *(__half2*)&hlds[wv][pl][80] = __floats2half2_rn(c0z, 0.f);
#pragma unroll
        for (int j2 = 41; j2 < 48; ++j2)
            *(__half2*)&hlds[wv][pl][2 * j2] = __floats2half2_rn(0.f, 0.f);
    }
    LDS_FENCE();

    const int fr = lane & 15, fg = lane >> 4;
    // comb A-frags held in regs for both chains' layer 0
    f16x8 cfr[2][3];
#pragma unroll
    for (int t2 = 0; t2 < 2; ++t2)
#pragma unroll
        for (int kt = 0; kt < 3; ++kt)
            cfr[t2][kt] = *(const f16x8*)&hlds[wv][t2 * 16 + fr][kt * 32 + fg * 8];
    LDS_FENCE();  // reads complete before layer-0 writes overwrite rows

    float yc[2];
    for (int chain = 0; chain < 2; ++chain) {
        const int idx = STAGE * 2 + chain;
        // ---- layer 0 (K=96, 3 k-tiles) ----
        {
            const _Float16* wfb = W0f + (idx * 3) * 8 * 1024;
            const float* bias = b0 + idx * 128;
            for (int n0 = 0; n0 < 8; ++n0) {
                f16x8 bh[3], bl[3];
#pragma unroll
                for (int kt = 0; kt < 3; ++kt) {
                    const _Float16* cb2 = wfb + (kt * 8 + n0) * 1024;
                    bh[kt] = *(const f16x8*)(cb2 + lane * 8);
                    bl[kt] = *(const f16x8*)(cb2 + 512 + lane * 8);
                }
                const float bb = bias[n0 * 16 + fr];
                f32x4 acc0 = {bb, bb, bb, bb}, acc1 = {bb, bb, bb, bb};
#pragma unroll
                for (int kt = 0; kt < 3; ++kt) {
                    acc0 = __builtin_amdgcn_mfma_f32_16x16x32_f16(cfr[0][kt], bh[kt], acc0, 0, 0, 0);
                    acc1 = __builtin_amdgcn_mfma_f32_16x16x32_f16(cfr[1][kt], bh[kt], acc1, 0, 0, 0);
                    acc0 = __builtin_amdgcn_mfma_f32_16x16x32_f16(cfr[0][kt], bl[kt], acc0, 0, 0, 0);
                    acc1 = __builtin_amdgcn_mfma_f32_16x16x32_f16(cfr[1][kt], bl[kt], acc1, 0, 0, 0);
                }
#pragma unroll
                for (int t2 = 0; t2 < 2; ++t2) {
                    const f32x4 a = t2 ? acc1 : acc0;
#pragma unroll
                    for (int rg = 0; rg < 4; ++rg) {
                        const float v = a[rg];
                        const float sv = v * __builtin_amdgcn_rcpf(1.f + __expf(-v));
                        hlds[wv][t2 * 16 + fg * 4 + rg][n0 * 16 + fr] = (_Float16)sv;
                    }
                }
            }
        }
        LDS_FENCE();
        // ---- layers 1..3 (K=128, 4 k-tiles), in-place h update ----
        for (int l = 0; l < 3; ++l) {
            f16x8 afr[2][4];
#pragma unroll
            for (int t2 = 0; t2 < 2; ++t2)
#pragma unroll
                for (int kt = 0; kt < 4; ++kt)
                    afr[t2][kt] = *(const f16x8*)&hlds[wv][t2 * 16 + fr][kt * 32 + fg * 8];
            const _Float16* wfb = W1f + ((idx * 3 + l) * 4) * 8 * 1024;
            const float* bias = b1 + (idx * 3 + l) * 128;
            for (int n0 = 0; n0 < 8; ++n0) {
                f16x8 bh[4], bl[4];
#pragma unroll
                for (int kt = 0; kt < 4; ++kt) {
                    const _Float16* cb2 = wfb + (kt * 8 + n0) * 1024;
                    bh[kt] = *(const f16x8*)(cb2 + lane * 8);
                    bl[kt] = *(const f16x8*)(cb2 + 512 + lane * 8);
                }
                const float bb = bias[n0 * 16 + fr];
                f32x4 acc0 = {bb, bb, bb, bb}, acc1 = {bb, bb, bb, bb};
#pragma unroll
                for (int kt = 0; kt < 4; ++kt) {
                    acc0 = __builtin_amdgcn_mfma_f32_16x16x32_f16(afr[0][kt], bh[kt], acc0, 0, 0, 0);
                    acc1 = __builtin_amdgcn_mfma_f32_16x16x32_f16(afr[1][kt], bh[kt], acc1, 0, 0, 0);
                    acc0 = __builtin_amdgcn_mfma_f32_16x16x32_f16(afr[0][kt], bl[kt], acc0, 0, 0, 0);
                    acc1 = __builtin_amdgcn_mfma_f32_16x16x32_f16(afr[1][kt], bl[kt], acc1, 0, 0, 0);
                }
#pragma unroll
                for (int t2 = 0; t2 < 2; ++t2) {
                    const f32x4 a = t2 ? acc1 : acc0;
#pragma unroll
                    for (int rg = 0; rg < 4; ++rg) {
                        const float v = a[rg];
                        const float sv = v * __builtin_amdgcn_rcpf(1.f + __expf(-v));
                        hlds[wv][t2 * 16 + fg * 4 + rg][n0 * 16 + fr] = (_Float16)sv;
                    }
                }
            }
            LDS_FENCE();
        }
        // ---- final dot: y = h3 . w2 + b2 (lanes split K by hh) ----
        {
            const _Float16* hrow = &hlds[wv][pl][0];
            const _Float16* w2row = &w2l[idx][0];
            const int kb = hh * 64;
            float part = 0.f;
#pragma unroll 8
            for (int j = 0; j < 32; ++j) {
                const float2 hf = __half22float2(*(const __half2*)&hrow[kb + 2 * j]);
                const float2 wf = __half22float2(*(const __half2*)&w2row[kb + 2 * j]);
                part = fmaf(hf.x, wf.x, part);
                part = fmaf(hf.y, wf.y, part);
            }
            part += __shfl_xor(part, 32);
            yc[chain] = part + b2[idx];
        }
        LDS_FENCE();  // dot reads drained before chain-t layer-0 overwrites h
    }

    const float s = 1.5f * tanhf(yc[0]);
    const float zn = fmaf(zmod, expf(s), yc[1]);
    if (lane < 32) out[2 * p + STAGE] = zn;

    float sv = (lane < 32) ? s : 0.f;
#pragma unroll
    for (int off = 1; off <= 16; off <<= 1) sv += __shfl_xor(sv, off);
    if (lane == 0) atomicAdd(out + ZSIZE + b, sv);
}

// ---------------------------------------------------------------------------
extern "C" void kernel_launch(void* const* d_in, const int* in_sizes, int n_in,
                              void* d_out, int out_size, void* d_ws, size_t ws_size,
                              hipStream_t stream) {
    const float* x = (const float*)d_in[0];
    const float* w = (const float*)d_in[1];
    const float* cond = (const float*)d_in[2];
    const float* W0 = (const float*)d_in[3];
    const float* b0 = (const float*)d_in[4];
    const float* W1 = (const float*)d_in[5];
    const float* b1 = (const float*)d_in[6];
    const float* W2 = (const float*)d_in[7];
    const float* b2 = (const float*)d_in[8];
    float* out = (float*)d_out;

    _Float16* W0f = (_Float16*)d_ws;
    _Float16* W1f = W0f + W0F_HALFS;
    _Float16* W2h = W1f + W1F_HALFS;  // total ~0.94 MB

    prep_kernel<<<256, 256, 0, stream>>>(W0, W1, W2, W0f, W1f, W2h, out + ZSIZE);
    stage_kernel<0><<<2048, 256, 0, stream>>>(x, w, cond, W0f, b0, W1f, b1, W2h, b2, out);
    stage_kernel<1><<<2048, 256, 0, stream>>>(x, w, cond, W0f, b0, W1f, b1, W2h, b2, out);
}